// Round 24
// baseline (123.592 us; speedup 1.0000x reference)
//
#include <hip/hip_runtime.h>
#include <hip/hip_bf16.h>

typedef short short8 __attribute__((ext_vector_type(8)));
typedef float f32x4 __attribute__((ext_vector_type(4)));
typedef unsigned short u16;
typedef u16 u16x4 __attribute__((ext_vector_type(4)));
typedef unsigned int u32;
typedef u32 u32x4 __attribute__((ext_vector_type(4)));

#define MFMA __builtin_amdgcn_mfma_f32_16x16x32_bf16
#define EXP2 __builtin_amdgcn_exp2f

#define HEADS 8
#define HD 64
#define CDIM 512
#define K3 1536
#define NH 2048
#define NP 512
#define NB 2
#define M_HIST (NB*NH)                 // 4096
#define M_PATH (NB*NP)                 // 1024
#define M_TOT  (M_HIST + M_PATH + NB)  // 5122
#define M_PAD  5248                    // 41*128
#define ATT_SCALE 0.125f
#define SCALE_LOG2E 0.1803368801f      // 0.125 * log2(e)
#define NKG (1 + NH + NP)              // 2561 keys for global cross-attn
#define GCHUNK 256
#define NCHUNK 11                      // ceil(2561/256)
#define KS 4                           // K-split for self-attn

__device__ __forceinline__ u16 f2bf(float f) {
    unsigned u = __builtin_bit_cast(unsigned int, f);
    u += 0x7fffu + ((u >> 16) & 1u);
    return (u16)(u >> 16);
}
__device__ __forceinline__ float bf2f(u16 u) {
    return __builtin_bit_cast(float, ((unsigned)u) << 16);
}
__device__ __forceinline__ u32 cvtpk(float lo, float hi) {
    u32 r;
    asm("v_cvt_pk_bf16_f32 %0, %1, %2" : "=v"(r) : "v"(lo), "v"(hi));
    return r;
}
// load 8 consecutive f32, convert to bf16x8 (RNE, identical to old convert_kernel)
__device__ __forceinline__ short8 cvt8(const float* p) {
    float4 v0 = *(const float4*)p, v1 = *(const float4*)(p + 4);
    short8 r;
    r[0] = (short)f2bf(v0.x); r[1] = (short)f2bf(v0.y);
    r[2] = (short)f2bf(v0.z); r[3] = (short)f2bf(v0.w);
    r[4] = (short)f2bf(v1.x); r[5] = (short)f2bf(v1.y);
    r[6] = (short)f2bf(v1.z); r[7] = (short)f2bf(v1.w);
    return r;
}
// X-concat row -> source pointer (nullptr = zero pad row), offset in elements
__device__ __forceinline__ const float* xsrc(const float* h, const float* p, const float* g,
                                             int row, int off) {
    if (row < M_HIST)          return h + (size_t)row * CDIM + off;
    if (row < M_HIST + M_PATH) return p + (size_t)(row - M_HIST) * CDIM + off;
    if (row < M_TOT)           return g + (size_t)(row - M_HIST - M_PATH) * CDIM + off;
    return nullptr;
}

// ---------------- GEMM 128x128 tile, reg-staged LDS, fused f32->bf16 conversion ----------------
// MODE 0: A = X-concat (f32, 3 sources), B = wqkv (f32); epilogue scatters V into vth/vtp.
// MODE 1: A = xatt (bf16), B = wproj (f32); f32 out + bias, row-guarded.
template<int MODE>
__global__ __launch_bounds__(256)
void gemm128(const float* __restrict__ histf, const float* __restrict__ pathf,
             const float* __restrict__ globf, const u16* __restrict__ Abf,
             const float* __restrict__ Bf,
             u16* __restrict__ outb, float* __restrict__ outf,
             const float* __restrict__ bias, int N,
             u16* __restrict__ vth, u16* __restrict__ vtp)
{
    const int t = threadIdx.x;
    const int l = t & 63, wave = t >> 6;
    const int lr = l & 15, lg = l >> 4;
    const int wr = wave >> 1, wc = wave & 1;
    const int n0 = blockIdx.x * 128, m0 = blockIdx.y * 128;

    __shared__ __align__(16) u16 als[2][128 * 32];
    __shared__ __align__(16) u16 bls[2][128 * 32];

    const int sr = t >> 2, sc = t & 3;
    const int ar0 = m0 + sr, ar1 = m0 + 64 + sr;
    const float *aF0 = nullptr, *aF1 = nullptr;
    const u16 *aB0 = nullptr, *aB1 = nullptr;
    if constexpr (MODE == 0) {
        aF0 = xsrc(histf, pathf, globf, ar0, sc * 8);
        aF1 = xsrc(histf, pathf, globf, ar1, sc * 8);
    } else {
        aB0 = Abf + (size_t)ar0 * CDIM + sc * 8;
        aB1 = Abf + (size_t)ar1 * CDIM + sc * 8;
    }
    const float* bF0 = Bf + (size_t)(n0 + sr) * CDIM + sc * 8;
    const float* bF1 = Bf + (size_t)(n0 + 64 + sr) * CDIM + sc * 8;
    const int da0 = sr * 32 + ((sc ^ (sr & 3)) * 8);
    const int da1 = (64 + sr) * 32 + ((sc ^ (sr & 3)) * 8);

    const short8 z8 = {0, 0, 0, 0, 0, 0, 0, 0};
#define LDA0(KO) ((MODE == 0) ? (aF0 ? cvt8(aF0 + (KO)) : z8) : *(const short8*)(aB0 + (KO)))
#define LDA1(KO) ((MODE == 0) ? (aF1 ? cvt8(aF1 + (KO)) : z8) : *(const short8*)(aB1 + (KO)))

    f32x4 acc[4][4] = {};

    short8 ra0 = LDA0(0), ra1 = LDA1(0);
    short8 rb0 = cvt8(bF0), rb1 = cvt8(bF1);
    *(short8*)&als[0][da0] = ra0; *(short8*)&als[0][da1] = ra1;
    *(short8*)&bls[0][da0] = rb0; *(short8*)&bls[0][da1] = rb1;
    ra0 = LDA0(32); ra1 = LDA1(32);
    rb0 = cvt8(bF0 + 32); rb1 = cvt8(bF1 + 32);
    __syncthreads();

#pragma unroll 2
    for (int kt = 0; kt < 16; kt++) {
        const int cur = kt & 1;
        if (kt + 1 < 16) {
            *(short8*)&als[cur ^ 1][da0] = ra0; *(short8*)&als[cur ^ 1][da1] = ra1;
            *(short8*)&bls[cur ^ 1][da0] = rb0; *(short8*)&bls[cur ^ 1][da1] = rb1;
            if (kt + 2 < 16) {
                const int ko = (kt + 2) * 32;
                ra0 = LDA0(ko); ra1 = LDA1(ko);
                rb0 = cvt8(bF0 + ko); rb1 = cvt8(bF1 + ko);
            }
        }
        short8 fa[4], fb[4];
#pragma unroll
        for (int i = 0; i < 4; i++) {
            int row = wr * 64 + i * 16 + lr;
            fa[i] = *(const short8*)&als[cur][row * 32 + ((lg ^ (lr & 3)) * 8)];
        }
#pragma unroll
        for (int j = 0; j < 4; j++) {
            int row = wc * 64 + j * 16 + lr;
            fb[j] = *(const short8*)&bls[cur][row * 32 + ((lg ^ (lr & 3)) * 8)];
        }
#pragma unroll
        for (int i = 0; i < 4; i++)
#pragma unroll
            for (int j = 0; j < 4; j++)
                acc[i][j] = MFMA(fa[i], fb[j], acc[i][j], 0, 0, 0);
        __syncthreads();
    }
#undef LDA0
#undef LDA1

#pragma unroll
    for (int i = 0; i < 4; i++)
#pragma unroll
        for (int j = 0; j < 4; j++) {
            const int rowb = m0 + wr * 64 + i * 16 + lg * 4;
            const int col  = n0 + wc * 64 + j * 16 + lr;
#pragma unroll
            for (int r = 0; r < 4; r++) {
                int row = rowb + r;
                if (MODE == 0) {
                    outb[(size_t)row * N + col] = f2bf(acc[i][j][r]);
                } else if (row < M_TOT) {
                    outf[(size_t)row * N + col] = acc[i][j][r] + bias[col];
                }
            }
            // fused V-transpose: V cols -> vt[bh][d][n] (4 consecutive n = one 8B store)
            if (MODE == 0 && col >= 2 * CDIM) {
                const int h = (col - 2 * CDIM) >> 6, d = (col - 2 * CDIM) & 63;
                u16x4 vv;
#pragma unroll
                for (int r = 0; r < 4; r++) vv[r] = f2bf(acc[i][j][r]);
                if (rowb < M_HIST) {
                    int b = rowb >> 11, n = rowb & 2047;
                    *(u16x4*)&vth[((size_t)(b * 8 + h) * HD + d) * NH + n] = vv;
                } else if (rowb < M_HIST + M_PATH) {
                    int rp = rowb - M_HIST;
                    int b = rp >> 9, n = rp & 511;
                    *(u16x4*)&vtp[((size_t)(b * 8 + h) * HD + d) * NP + n] = vv;
                }
            }
        }
}

// ---------------- self-attention tile (r15-verified body) ----------------
__device__ __forceinline__ void attn_tile(const u16* __restrict__ kbuf, const u16* __restrict__ vbuf,
                                          const short8 (&qa)[2][2], f32x4 (&o)[2][4],
                                          f32x4 (&o1)[2], int lr, int lg)
{
    const short8 vones = {0x3F80, 0x3F80, 0x3F80, 0x3F80, 0x3F80, 0x3F80, 0x3F80, 0x3F80};
    short8 kf[2][2], vb[4];
#pragma unroll
    for (int kt = 0; kt < 2; kt++)
#pragma unroll
        for (int kss = 0; kss < 2; kss++)
            kf[kt][kss] = *(const short8*)&kbuf[(kt*16 + lr)*64 + (((kss<<2) + lg) ^ (lr & 7))*8];
#pragma unroll
    for (int dt = 0; dt < 4; dt++)
        vb[dt] = *(const short8*)&vbuf[(dt*16 + lr)*32 + ((lg ^ ((lr >> 1) & 3)))*8];

    f32x4 st[2][2] = {};
#pragma unroll
    for (int kt = 0; kt < 2; kt++)
#pragma unroll
        for (int qt = 0; qt < 2; qt++) {
            st[kt][qt] = MFMA(kf[kt][0], qa[qt][0], st[kt][qt], 0, 0, 0);
            st[kt][qt] = MFMA(kf[kt][1], qa[qt][1], st[kt][qt], 0, 0, 0);
        }

    const bool odd = lg & 1;
    short8 pa[2];
#pragma unroll
    for (int qt = 0; qt < 2; qt++) {
        float p[8];
#pragma unroll
        for (int r = 0; r < 4; r++) {
            p[r]     = EXP2(st[0][qt][r] * SCALE_LOG2E);
            p[4 + r] = EXP2(st[1][qt][r] * SCALE_LOG2E);
        }
        u32 w0 = cvtpk(p[0], p[1]), w1 = cvtpk(p[2], p[3]);
        u32 w2 = cvtpk(p[4], p[5]), w3 = cvtpk(p[6], p[7]);
        u32 s0 = __shfl_xor(w0, 16, 64), s1 = __shfl_xor(w1, 16, 64);
        u32 s2 = __shfl_xor(w2, 16, 64), s3 = __shfl_xor(w3, 16, 64);
        u32 k0q[4], k1q[4];
        k0q[0] = odd ? s0 : w0; k0q[1] = odd ? s1 : w1;
        k0q[2] = odd ? w0 : s0; k0q[3] = odd ? w1 : s1;
        k1q[0] = odd ? s2 : w2; k1q[1] = odd ? s3 : w3;
        k1q[2] = odd ? w2 : s2; k1q[3] = odd ? w3 : s3;
        u32x4 F;
#pragma unroll
        for (int i = 0; i < 4; i++) {
            u32 r0 = k0q[i], r1 = k1q[i];
            asm("v_permlane32_swap_b32 %0, %1" : "+v"(r0), "+v"(r1));
            F[i] = (lg & 1) ? r1 : r0;
        }
        pa[qt] = __builtin_bit_cast(short8, F);
    }

#pragma unroll
    for (int dt = 0; dt < 4; dt++) {
        o[0][dt] = MFMA(pa[0], vb[dt], o[0][dt], 0, 0, 0);
        o[1][dt] = MFMA(pa[1], vb[dt], o[1][dt], 0, 0, 0);
    }
    o1[0] = MFMA(pa[0], vones, o1[0], 0, 0, 0);
    o1[1] = MFMA(pa[1], vones, o1[1], 0, 0, 0);
}

__device__ __forceinline__ void attn_self_body(u16* smem, const u16* __restrict__ qkv,
                                               const u16* __restrict__ vt,
                                               u16* __restrict__ opart, float* __restrict__ lpart,
                                               int Nloc, int row_base, int bh, int ytile, int ks)
{
    const int b = bh >> 3, h = bh & 7;
    const int t = threadIdx.x;
    const int l = t & 63;
    const int lr = l & 15, lg = l >> 4;
    const int wave = t >> 6;
    const int q0 = ytile * 128 + wave * 32;
    const int kpb = Nloc / KS;
    const int kbeg = ks * kpb;
    const int T = kpb / 32;

    u16 (*kls)[2048] = (u16(*)[2048])smem;
    u16 (*vls)[2048] = (u16(*)[2048])(smem + 4096);

    const u16* qbase = qkv + ((size_t)row_base + (size_t)b * Nloc) * K3 + h * HD;
    const u16* kbase = qbase + CDIM;
    const u16* vtb   = vt + (size_t)bh * HD * Nloc;

    const int krow = t >> 3, kch = t & 7;
    const int vrow = t >> 2, vch = t & 3;
    const int kdoff = krow * 64 + (kch ^ (krow & 7)) * 8;
    const int vdoff = vrow * 32 + (vch ^ ((vrow >> 1) & 3)) * 8;
    const u16* kp = kbase + (size_t)(kbeg + krow) * K3 + kch * 8;
    const u16* vp = vtb + (size_t)vrow * Nloc + kbeg + vch * 8;
    const size_t kstep = 32 * (size_t)K3, vstep = 32;

    short8 qa[2][2];
#pragma unroll
    for (int qt = 0; qt < 2; qt++)
#pragma unroll
        for (int kss = 0; kss < 2; kss++)
            qa[qt][kss] = *(const short8*)(qbase + (size_t)(q0 + qt*16 + lr) * K3 + kss*32 + lg*8);

    f32x4 o[2][4] = {};
    f32x4 o1[2] = {};

    short8 kreg = *(const short8*)kp; kp += kstep;
    short8 vreg = *(const short8*)vp; vp += vstep;
    *(short8*)&kls[0][kdoff] = kreg;
    *(short8*)&vls[0][vdoff] = vreg;
    kreg = *(const short8*)kp; kp += kstep;
    vreg = *(const short8*)vp; vp += vstep;
    __syncthreads();

    for (int i = 0; i < T; i++) {
        const int cur = i & 1;
        if (i + 1 < T) {
            *(short8*)&kls[cur ^ 1][kdoff] = kreg;
            *(short8*)&vls[cur ^ 1][vdoff] = vreg;
            if (i + 2 < T) {
                kreg = *(const short8*)kp; kp += kstep;
                vreg = *(const short8*)vp; vp += vstep;
            }
        }
        attn_tile(kls[cur], vls[cur], qa, o, o1, lr, lg);
        __syncthreads();
    }

#pragma unroll
    for (int qt = 0; qt < 2; qt++)
        if (lr == 0)
#pragma unroll
            for (int r = 0; r < 4; r++) {
                size_t lrow = (size_t)b * Nloc + q0 + qt*16 + lg*4 + r;
                lpart[(lrow * HEADS + h) * KS + ks] = o1[qt][r];
            }
#pragma unroll
    for (int qt = 0; qt < 2; qt++)
#pragma unroll
        for (int dt = 0; dt < 4; dt++)
#pragma unroll
            for (int r = 0; r < 4; r++) {
                size_t lrow = (size_t)b * Nloc + q0 + qt*16 + lg*4 + r;
                opart[((lrow * HEADS + h) * KS + ks) * HD + dt*16 + lr] = f2bf(o[qt][dt][r]);
            }
}

// ---------------- global-token cross-attention body (r15-verified) ----------------
__device__ __forceinline__ size_t gk_row(int k, int b) {
    if (k == 0) return (size_t)(M_HIST + M_PATH + b);
    if (k <= NH) return (size_t)(b * NH + (k - 1));
    return (size_t)(M_HIST + b * NP + (k - 1 - NH));
}

__device__ __forceinline__ void attn_global_body(float* qs, float* ps, float* red, float (*ored)[HD],
                                                 const u16* __restrict__ qkv,
                                                 float* __restrict__ gm, float* __restrict__ gl,
                                                 float* __restrict__ go, int bh, int chunk)
{
    const int b = bh >> 3, h = bh & 7;
    const int t = threadIdx.x;
    const int k0 = chunk * GCHUNK;
    const int k = k0 + t;
    const bool valid = (k < NKG);

    if (t < HD) qs[t] = bf2f(qkv[(size_t)(M_HIST + M_PATH + b) * K3 + h * HD + t]);
    __syncthreads();

    float s = -INFINITY;
    if (valid) {
        const u16* kr = qkv + gk_row(k, b) * K3 + CDIM + h * HD;
        float acc = 0.f;
#pragma unroll
        for (int dv = 0; dv < 8; dv++) {
            short8 kv = *(const short8*)(kr + dv * 8);
#pragma unroll
            for (int j = 0; j < 8; j++) acc += qs[dv * 8 + j] * bf2f((u16)kv[j]);
        }
        s = acc * ATT_SCALE;
    }

    float m = s;
#pragma unroll
    for (int off = 1; off < 64; off <<= 1) m = fmaxf(m, __shfl_xor(m, off, 64));
    if ((t & 63) == 0) red[t >> 6] = m;
    __syncthreads();
    m = fmaxf(fmaxf(red[0], red[1]), fmaxf(red[2], red[3]));

    float p = valid ? __expf(s - m) : 0.f;
    ps[t] = p;

    float l = p;
#pragma unroll
    for (int off = 1; off < 64; off <<= 1) l += __shfl_xor(l, off, 64);
    __syncthreads();
    if ((t & 63) == 0) red[t >> 6] = l;
    __syncthreads();
    l = red[0] + red[1] + red[2] + red[3];

    const int d = t & 63, part = t >> 6;
    float acc = 0.f;
#pragma unroll 4
    for (int kk = part * 64; kk < part * 64 + 64; kk++) {
        int kg = k0 + kk;
        if (kg < NKG)
            acc += ps[kk] * bf2f(qkv[gk_row(kg, b) * K3 + 2 * CDIM + h * HD + d]);
    }
    ored[part][d] = acc;
    __syncthreads();
    if (part == 0) {
        float o = ored[0][d] + ored[1][d] + ored[2][d] + ored[3][d];
        go[((size_t)bh * NCHUNK + chunk) * HD + d] = o;
        if (d == 0) {
            gm[bh * NCHUNK + chunk] = m;
            gl[bh * NCHUNK + chunk] = l;
        }
    }
}

// ---------------- merged attention, XCD-pinned bh mapping ----------------
__global__ __launch_bounds__(256)
void attn_mega(const u16* __restrict__ qkv, const u16* __restrict__ vth, const u16* __restrict__ vtp,
               u16* __restrict__ opart_h, float* __restrict__ lpart_h,
               u16* __restrict__ opart_p, float* __restrict__ lpart_p,
               float* __restrict__ gm, float* __restrict__ gl, float* __restrict__ go)
{
    __shared__ __align__(16) u16 smem[8192];
    __shared__ float gqs[HD];
    __shared__ float gps[GCHUNK];
    __shared__ float gred[4];
    __shared__ float gored[4][HD];
    int blk = blockIdx.x;
    if (blk < 1024) {               // hist: xcd-pinned bh
        int xcd = blk & 7, i = blk >> 3;
        int bh = xcd + 8 * (i & 1);
        int rem = i >> 1;
        int y = rem & 15, ks = rem >> 4;
        attn_self_body(smem, qkv, vth, opart_h, lpart_h, NH, 0, bh, y, ks);
    } else if (blk < 1280) {        // path
        blk -= 1024;
        int xcd = blk & 7, i = blk >> 3;
        int bh = xcd + 8 * (i & 1);
        int rem = i >> 1;
        int y = rem & 3, ks = rem >> 2;
        attn_self_body(smem, qkv, vtp, opart_p, lpart_p, NP, M_HIST, bh, y, ks);
    } else {                        // global
        blk -= 1280;
        int bh = blk & 15, chunk = blk >> 4;
        attn_global_body(gqs, gps, gred, gored, qkv, gm, gl, go, bh, chunk);
    }
}

// ---------------- merged epilogue: global reduce (first) | hist combine | path combine ----------------
__global__ __launch_bounds__(256)
void epilogue2(const u16* __restrict__ opart_h, const float* __restrict__ lpart_h,
               const u16* __restrict__ opart_p, const float* __restrict__ lpart_p,
               const float* __restrict__ gm, const float* __restrict__ gl,
               const float* __restrict__ go, u16* __restrict__ xattn)
{
    const int blk = blockIdx.x;
    const int t = threadIdx.x;
    if (blk < 4) {
        int gid = blk * 256 + t;
        int bh = gid >> 6, d = gid & 63;
        int b = bh >> 3, h = bh & 7;
        float m = -INFINITY;
#pragma unroll
        for (int c = 0; c < NCHUNK; c++) m = fmaxf(m, gm[bh * NCHUNK + c]);
        float den = 0.f, acc = 0.f;
#pragma unroll
        for (int c = 0; c < NCHUNK; c++) {
            float w = __expf(gm[bh * NCHUNK + c] - m);
            den += w * gl[bh * NCHUNK + c];
            acc += w * go[((size_t)bh * NCHUNK + c) * HD + d];
        }
        xattn[(size_t)(M_HIST + M_PATH + b) * CDIM + h * HD + d] = f2bf(acc / den);
    } else {
        const u16* opart; const float* lpart; int row_base, idx;
        if (blk < 4 + 8192) { opart = opart_h; lpart = lpart_h; row_base = 0;      idx = (blk - 4) * 256 + t; }
        else                { opart = opart_p; lpart = lpart_p; row_base = M_HIST; idx = (blk - 4 - 8192) * 256 + t; }
        int grow = idx >> 9;
        int c = idx & 511;
        int h = c >> 6, d = c & 63;
        size_t pb = ((size_t)grow * HEADS + h) * KS;
        float O = 0.f, L = 0.f;
#pragma unroll
        for (int s = 0; s < KS; s++) {
            O += bf2f(opart[(pb + s) * HD + d]);
            L += lpart[pb + s];
        }
        xattn[(size_t)(row_base + grow) * CDIM + c] = f2bf(O / L);
    }
}

// ---------------- launch ----------------
extern "C" void kernel_launch(void* const* d_in, const int* in_sizes, int n_in,
                              void* d_out, int out_size, void* d_ws, size_t ws_size,
                              hipStream_t stream)
{
    const float* hist  = (const float*)d_in[0];
    const float* path  = (const float*)d_in[1];
    const float* glob  = (const float*)d_in[2];
    const float* wqkv  = (const float*)d_in[3];
    const float* wproj = (const float*)d_in[4];
    const float* bias  = (const float*)d_in[5];
    float* out = (float*)d_out;

    u16* qkvb = (u16*)d_ws;
    u16* vth  = qkvb + (size_t)M_PAD * K3;
    u16* vtp  = vth  + (size_t)NB * HEADS * HD * NH;
    u16* xatt = vtp  + (size_t)NB * HEADS * HD * NP;
    float* gm = (float*)(xatt + (size_t)M_PAD * CDIM);
    float* gl = gm + NB * HEADS * NCHUNK;
    float* go = gl + NB * HEADS * NCHUNK;
    float* lpart_h = go + (size_t)NB * HEADS * NCHUNK * HD;
    float* lpart_p = lpart_h + (size_t)M_HIST * HEADS * KS;
    u16* opart_h = (u16*)(lpart_p + (size_t)M_PATH * HEADS * KS);
    u16* opart_p = opart_h + (size_t)M_HIST * HEADS * KS * HD;

    gemm128<0><<<dim3(K3 / 128, M_PAD / 128), 256, 0, stream>>>(hist, path, glob, nullptr, wqkv,
                                                                qkvb, nullptr, nullptr, K3,
                                                                vth, vtp);
    attn_mega<<<1456, 256, 0, stream>>>(qkvb, vth, vtp, opart_h, lpart_h, opart_p, lpart_p,
                                        gm, gl, go);
    epilogue2<<<4 + 8192 + 2048, 256, 0, stream>>>(opart_h, lpart_h, opart_p, lpart_p,
                                                   gm, gl, go, xatt);
    gemm128<1><<<dim3(CDIM / 128, M_PAD / 128), 256, 0, stream>>>(nullptr, nullptr, nullptr, xatt,
                                                                  wproj, nullptr, out, bias, CDIM,
                                                                  nullptr, nullptr);
}

// Round 25
// 109.961 us; speedup vs baseline: 1.1240x; 1.1240x over previous
//
#include <hip/hip_runtime.h>
#include <hip/hip_bf16.h>

typedef short short8 __attribute__((ext_vector_type(8)));
typedef float f32x4 __attribute__((ext_vector_type(4)));
typedef unsigned short u16;
typedef u16 u16x4 __attribute__((ext_vector_type(4)));
typedef unsigned int u32;
typedef u32 u32x4 __attribute__((ext_vector_type(4)));

#define MFMA __builtin_amdgcn_mfma_f32_16x16x32_bf16
#define EXP2 __builtin_amdgcn_exp2f

#define HEADS 8
#define HD 64
#define CDIM 512
#define K3 1536
#define NH 2048
#define NP 512
#define NB 2
#define M_HIST (NB*NH)                 // 4096
#define M_PATH (NB*NP)                 // 1024
#define M_TOT  (M_HIST + M_PATH + NB)  // 5122
#define M_PAD  5248                    // 41*128
#define ATT_SCALE 0.125f
#define SCALE_LOG2E 0.1803368801f      // 0.125 * log2(e)
#define NKG (1 + NH + NP)              // 2561 keys for global cross-attn
#define GCHUNK 256
#define NCHUNK 11                      // ceil(2561/256)
#define KS 4                           // K-split for self-attn

__device__ __forceinline__ u16 f2bf(float f) {
    unsigned u = __builtin_bit_cast(unsigned int, f);
    u += 0x7fffu + ((u >> 16) & 1u);
    return (u16)(u >> 16);
}
__device__ __forceinline__ float bf2f(u16 u) {
    return __builtin_bit_cast(float, ((unsigned)u) << 16);
}
__device__ __forceinline__ u32 cvtpk(float lo, float hi) {
    u32 r;
    asm("v_cvt_pk_bf16_f32 %0, %1, %2" : "=v"(r) : "v"(lo), "v"(hi));
    return r;
}

// ---------------- convert f32 -> bf16 (X concat + weights) ----------------
__global__ void convert_kernel(const float* __restrict__ hist, const float* __restrict__ path,
                               const float* __restrict__ glob, const float* __restrict__ wqkv,
                               const float* __restrict__ wproj,
                               u16* __restrict__ xcat, u16* __restrict__ wq, u16* __restrict__ wp)
{
    const int NX  = M_PAD * CDIM / 4;
    const int NWQ = K3 * CDIM / 4;
    const int NWP = CDIM * CDIM / 4;
    int qi = blockIdx.x * 256 + threadIdx.x;
    float4 v = make_float4(0.f, 0.f, 0.f, 0.f);
    u16* dst;
    if (qi < NX) {
        int e = qi * 4;
        int row = e >> 9;
        if (row < M_HIST)              v = *(const float4*)(hist + e);
        else if (row < M_HIST+M_PATH)  v = *(const float4*)(path + (e - M_HIST*CDIM));
        else if (row < M_TOT)          v = *(const float4*)(glob + (e - (M_HIST+M_PATH)*CDIM));
        dst = xcat + e;
    } else if (qi < NX + NWQ) {
        int e = (qi - NX) * 4;
        v = *(const float4*)(wqkv + e);
        dst = wq + e;
    } else if (qi < NX + NWQ + NWP) {
        int e = (qi - NX - NWQ) * 4;
        v = *(const float4*)(wproj + e);
        dst = wp + e;
    } else return;
    u16x4 o;
    o[0] = f2bf(v.x); o[1] = f2bf(v.y); o[2] = f2bf(v.z); o[3] = f2bf(v.w);
    *(u16x4*)dst = o;
}

// ---------------- GEMM 128x128 tile, reg-staged LDS (r18-verified) ----------------
// MODE 0 epilogue additionally scatters V columns (>=1024) into vth/vtp transposed.
template<int MODE>
__global__ __launch_bounds__(256)
void gemm128(const u16* __restrict__ A, const u16* __restrict__ Bm,
             u16* __restrict__ outb, float* __restrict__ outf,
             const float* __restrict__ bias, int N,
             u16* __restrict__ vth, u16* __restrict__ vtp)
{
    const int t = threadIdx.x;
    const int l = t & 63, wave = t >> 6;
    const int lr = l & 15, lg = l >> 4;
    const int wr = wave >> 1, wc = wave & 1;
    const int n0 = blockIdx.x * 128, m0 = blockIdx.y * 128;

    __shared__ __align__(16) u16 als[2][128 * 32];
    __shared__ __align__(16) u16 bls[2][128 * 32];

    const int sr = t >> 2, sc = t & 3;
    const u16* ga0 = A  + (size_t)(m0 + sr) * CDIM + sc * 8;
    const u16* ga1 = A  + (size_t)(m0 + 64 + sr) * CDIM + sc * 8;
    const u16* gb0 = Bm + (size_t)(n0 + sr) * CDIM + sc * 8;
    const u16* gb1 = Bm + (size_t)(n0 + 64 + sr) * CDIM + sc * 8;
    const int da0 = sr * 32 + ((sc ^ (sr & 3)) * 8);
    const int da1 = (64 + sr) * 32 + ((sc ^ (sr & 3)) * 8);

    f32x4 acc[4][4] = {};

    short8 ra0 = *(const short8*)ga0, ra1 = *(const short8*)ga1;
    short8 rb0 = *(const short8*)gb0, rb1 = *(const short8*)gb1;
    *(short8*)&als[0][da0] = ra0; *(short8*)&als[0][da1] = ra1;
    *(short8*)&bls[0][da0] = rb0; *(short8*)&bls[0][da1] = rb1;
    ra0 = *(const short8*)(ga0 + 32); ra1 = *(const short8*)(ga1 + 32);
    rb0 = *(const short8*)(gb0 + 32); rb1 = *(const short8*)(gb1 + 32);
    __syncthreads();

#pragma unroll 2
    for (int kt = 0; kt < 16; kt++) {
        const int cur = kt & 1;
        if (kt + 1 < 16) {
            *(short8*)&als[cur ^ 1][da0] = ra0; *(short8*)&als[cur ^ 1][da1] = ra1;
            *(short8*)&bls[cur ^ 1][da0] = rb0; *(short8*)&bls[cur ^ 1][da1] = rb1;
            if (kt + 2 < 16) {
                ra0 = *(const short8*)(ga0 + (kt + 2) * 32);
                ra1 = *(const short8*)(ga1 + (kt + 2) * 32);
                rb0 = *(const short8*)(gb0 + (kt + 2) * 32);
                rb1 = *(const short8*)(gb1 + (kt + 2) * 32);
            }
        }
        short8 fa[4], fb[4];
#pragma unroll
        for (int i = 0; i < 4; i++) {
            int row = wr * 64 + i * 16 + lr;
            fa[i] = *(const short8*)&als[cur][row * 32 + ((lg ^ (lr & 3)) * 8)];
        }
#pragma unroll
        for (int j = 0; j < 4; j++) {
            int row = wc * 64 + j * 16 + lr;
            fb[j] = *(const short8*)&bls[cur][row * 32 + ((lg ^ (lr & 3)) * 8)];
        }
#pragma unroll
        for (int i = 0; i < 4; i++)
#pragma unroll
            for (int j = 0; j < 4; j++)
                acc[i][j] = MFMA(fa[i], fb[j], acc[i][j], 0, 0, 0);
        __syncthreads();
    }

#pragma unroll
    for (int i = 0; i < 4; i++)
#pragma unroll
        for (int j = 0; j < 4; j++) {
            const int rowb = m0 + wr * 64 + i * 16 + lg * 4;
            const int col  = n0 + wc * 64 + j * 16 + lr;
#pragma unroll
            for (int r = 0; r < 4; r++) {
                int row = rowb + r;
                if (MODE == 0) {
                    outb[(size_t)row * N + col] = f2bf(acc[i][j][r]);
                } else if (row < M_TOT) {
                    outf[(size_t)row * N + col] = acc[i][j][r] + bias[col];
                }
            }
            // fused V-transpose: V cols -> vt[bh][d][n] (4 consecutive n = one 8B store)
            if (MODE == 0 && col >= 2 * CDIM) {
                const int h = (col - 2 * CDIM) >> 6, d = (col - 2 * CDIM) & 63;
                u16x4 vv;
#pragma unroll
                for (int r = 0; r < 4; r++) vv[r] = f2bf(acc[i][j][r]);
                if (rowb < M_HIST) {
                    int b = rowb >> 11, n = rowb & 2047;
                    *(u16x4*)&vth[((size_t)(b * 8 + h) * HD + d) * NH + n] = vv;
                } else if (rowb < M_HIST + M_PATH) {
                    int rp = rowb - M_HIST;
                    int b = rp >> 9, n = rp & 511;
                    *(u16x4*)&vtp[((size_t)(b * 8 + h) * HD + d) * NP + n] = vv;
                }
            }
        }
}

// ---------------- self-attention tile (r15-verified body) ----------------
__device__ __forceinline__ void attn_tile(const u16* __restrict__ kbuf, const u16* __restrict__ vbuf,
                                          const short8 (&qa)[2][2], f32x4 (&o)[2][4],
                                          f32x4 (&o1)[2], int lr, int lg)
{
    const short8 vones = {0x3F80, 0x3F80, 0x3F80, 0x3F80, 0x3F80, 0x3F80, 0x3F80, 0x3F80};
    short8 kf[2][2], vb[4];
#pragma unroll
    for (int kt = 0; kt < 2; kt++)
#pragma unroll
        for (int kss = 0; kss < 2; kss++)
            kf[kt][kss] = *(const short8*)&kbuf[(kt*16 + lr)*64 + (((kss<<2) + lg) ^ (lr & 7))*8];
#pragma unroll
    for (int dt = 0; dt < 4; dt++)
        vb[dt] = *(const short8*)&vbuf[(dt*16 + lr)*32 + ((lg ^ ((lr >> 1) & 3)))*8];

    f32x4 st[2][2] = {};
#pragma unroll
    for (int kt = 0; kt < 2; kt++)
#pragma unroll
        for (int qt = 0; qt < 2; qt++) {
            st[kt][qt] = MFMA(kf[kt][0], qa[qt][0], st[kt][qt], 0, 0, 0);
            st[kt][qt] = MFMA(kf[kt][1], qa[qt][1], st[kt][qt], 0, 0, 0);
        }

    const bool odd = lg & 1;
    short8 pa[2];
#pragma unroll
    for (int qt = 0; qt < 2; qt++) {
        float p[8];
#pragma unroll
        for (int r = 0; r < 4; r++) {
            p[r]     = EXP2(st[0][qt][r] * SCALE_LOG2E);
            p[4 + r] = EXP2(st[1][qt][r] * SCALE_LOG2E);
        }
        u32 w0 = cvtpk(p[0], p[1]), w1 = cvtpk(p[2], p[3]);
        u32 w2 = cvtpk(p[4], p[5]), w3 = cvtpk(p[6], p[7]);
        u32 s0 = __shfl_xor(w0, 16, 64), s1 = __shfl_xor(w1, 16, 64);
        u32 s2 = __shfl_xor(w2, 16, 64), s3 = __shfl_xor(w3, 16, 64);
        u32 k0q[4], k1q[4];
        k0q[0] = odd ? s0 : w0; k0q[1] = odd ? s1 : w1;
        k0q[2] = odd ? w0 : s0; k0q[3] = odd ? w1 : s1;
        k1q[0] = odd ? s2 : w2; k1q[1] = odd ? s3 : w3;
        k1q[2] = odd ? w2 : s2; k1q[3] = odd ? w3 : s3;
        u32x4 F;
#pragma unroll
        for (int i = 0; i < 4; i++) {
            u32 r0 = k0q[i], r1 = k1q[i];
            asm("v_permlane32_swap_b32 %0, %1" : "+v"(r0), "+v"(r1));
            F[i] = (lg & 1) ? r1 : r0;
        }
        pa[qt] = __builtin_bit_cast(short8, F);
    }

#pragma unroll
    for (int dt = 0; dt < 4; dt++) {
        o[0][dt] = MFMA(pa[0], vb[dt], o[0][dt], 0, 0, 0);
        o[1][dt] = MFMA(pa[1], vb[dt], o[1][dt], 0, 0, 0);
    }
    o1[0] = MFMA(pa[0], vones, o1[0], 0, 0, 0);
    o1[1] = MFMA(pa[1], vones, o1[1], 0, 0, 0);
}

__device__ __forceinline__ void attn_self_body(u16* smem, const u16* __restrict__ qkv,
                                               const u16* __restrict__ vt,
                                               u16* __restrict__ opart, float* __restrict__ lpart,
                                               int Nloc, int row_base, int bh, int ytile, int ks)
{
    const int b = bh >> 3, h = bh & 7;
    const int t = threadIdx.x;
    const int l = t & 63;
    const int lr = l & 15, lg = l >> 4;
    const int wave = t >> 6;
    const int q0 = ytile * 128 + wave * 32;
    const int kpb = Nloc / KS;
    const int kbeg = ks * kpb;
    const int T = kpb / 32;

    u16 (*kls)[2048] = (u16(*)[2048])smem;
    u16 (*vls)[2048] = (u16(*)[2048])(smem + 4096);

    const u16* qbase = qkv + ((size_t)row_base + (size_t)b * Nloc) * K3 + h * HD;
    const u16* kbase = qbase + CDIM;
    const u16* vtb   = vt + (size_t)bh * HD * Nloc;

    const int krow = t >> 3, kch = t & 7;
    const int vrow = t >> 2, vch = t & 3;
    const int kdoff = krow * 64 + (kch ^ (krow & 7)) * 8;
    const int vdoff = vrow * 32 + (vch ^ ((vrow >> 1) & 3)) * 8;
    const u16* kp = kbase + (size_t)(kbeg + krow) * K3 + kch * 8;
    const u16* vp = vtb + (size_t)vrow * Nloc + kbeg + vch * 8;
    const size_t kstep = 32 * (size_t)K3, vstep = 32;

    short8 qa[2][2];
#pragma unroll
    for (int qt = 0; qt < 2; qt++)
#pragma unroll
        for (int kss = 0; kss < 2; kss++)
            qa[qt][kss] = *(const short8*)(qbase + (size_t)(q0 + qt*16 + lr) * K3 + kss*32 + lg*8);

    f32x4 o[2][4] = {};
    f32x4 o1[2] = {};

    short8 kreg = *(const short8*)kp; kp += kstep;
    short8 vreg = *(const short8*)vp; vp += vstep;
    *(short8*)&kls[0][kdoff] = kreg;
    *(short8*)&vls[0][vdoff] = vreg;
    kreg = *(const short8*)kp; kp += kstep;
    vreg = *(const short8*)vp; vp += vstep;
    __syncthreads();

    for (int i = 0; i < T; i++) {
        const int cur = i & 1;
        if (i + 1 < T) {
            *(short8*)&kls[cur ^ 1][kdoff] = kreg;
            *(short8*)&vls[cur ^ 1][vdoff] = vreg;
            if (i + 2 < T) {
                kreg = *(const short8*)kp; kp += kstep;
                vreg = *(const short8*)vp; vp += vstep;
            }
        }
        attn_tile(kls[cur], vls[cur], qa, o, o1, lr, lg);
        __syncthreads();
    }

#pragma unroll
    for (int qt = 0; qt < 2; qt++)
        if (lr == 0)
#pragma unroll
            for (int r = 0; r < 4; r++) {
                size_t lrow = (size_t)b * Nloc + q0 + qt*16 + lg*4 + r;
                lpart[(lrow * HEADS + h) * KS + ks] = o1[qt][r];
            }
#pragma unroll
    for (int qt = 0; qt < 2; qt++)
#pragma unroll
        for (int dt = 0; dt < 4; dt++)
#pragma unroll
            for (int r = 0; r < 4; r++) {
                size_t lrow = (size_t)b * Nloc + q0 + qt*16 + lg*4 + r;
                opart[((lrow * HEADS + h) * KS + ks) * HD + dt*16 + lr] = f2bf(o[qt][dt][r]);
            }
}

// ---------------- global-token cross-attention body (r15-verified) ----------------
__device__ __forceinline__ size_t gk_row(int k, int b) {
    if (k == 0) return (size_t)(M_HIST + M_PATH + b);
    if (k <= NH) return (size_t)(b * NH + (k - 1));
    return (size_t)(M_HIST + b * NP + (k - 1 - NH));
}

__device__ __forceinline__ void attn_global_body(float* qs, float* ps, float* red, float (*ored)[HD],
                                                 const u16* __restrict__ qkv,
                                                 float* __restrict__ gm, float* __restrict__ gl,
                                                 float* __restrict__ go, int bh, int chunk)
{
    const int b = bh >> 3, h = bh & 7;
    const int t = threadIdx.x;
    const int k0 = chunk * GCHUNK;
    const int k = k0 + t;
    const bool valid = (k < NKG);

    if (t < HD) qs[t] = bf2f(qkv[(size_t)(M_HIST + M_PATH + b) * K3 + h * HD + t]);
    __syncthreads();

    float s = -INFINITY;
    if (valid) {
        const u16* kr = qkv + gk_row(k, b) * K3 + CDIM + h * HD;
        float acc = 0.f;
#pragma unroll
        for (int dv = 0; dv < 8; dv++) {
            short8 kv = *(const short8*)(kr + dv * 8);
#pragma unroll
            for (int j = 0; j < 8; j++) acc += qs[dv * 8 + j] * bf2f((u16)kv[j]);
        }
        s = acc * ATT_SCALE;
    }

    float m = s;
#pragma unroll
    for (int off = 1; off < 64; off <<= 1) m = fmaxf(m, __shfl_xor(m, off, 64));
    if ((t & 63) == 0) red[t >> 6] = m;
    __syncthreads();
    m = fmaxf(fmaxf(red[0], red[1]), fmaxf(red[2], red[3]));

    float p = valid ? __expf(s - m) : 0.f;
    ps[t] = p;

    float l = p;
#pragma unroll
    for (int off = 1; off < 64; off <<= 1) l += __shfl_xor(l, off, 64);
    __syncthreads();
    if ((t & 63) == 0) red[t >> 6] = l;
    __syncthreads();
    l = red[0] + red[1] + red[2] + red[3];

    const int d = t & 63, part = t >> 6;
    float acc = 0.f;
#pragma unroll 4
    for (int kk = part * 64; kk < part * 64 + 64; kk++) {
        int kg = k0 + kk;
        if (kg < NKG)
            acc += ps[kk] * bf2f(qkv[gk_row(kg, b) * K3 + 2 * CDIM + h * HD + d]);
    }
    ored[part][d] = acc;
    __syncthreads();
    if (part == 0) {
        float o = ored[0][d] + ored[1][d] + ored[2][d] + ored[3][d];
        go[((size_t)bh * NCHUNK + chunk) * HD + d] = o;
        if (d == 0) {
            gm[bh * NCHUNK + chunk] = m;
            gl[bh * NCHUNK + chunk] = l;
        }
    }
}

// ---------------- merged attention, XCD-pinned bh mapping ----------------
__global__ __launch_bounds__(256)
void attn_mega(const u16* __restrict__ qkv, const u16* __restrict__ vth, const u16* __restrict__ vtp,
               u16* __restrict__ opart_h, float* __restrict__ lpart_h,
               u16* __restrict__ opart_p, float* __restrict__ lpart_p,
               float* __restrict__ gm, float* __restrict__ gl, float* __restrict__ go)
{
    __shared__ __align__(16) u16 smem[8192];
    __shared__ float gqs[HD];
    __shared__ float gps[GCHUNK];
    __shared__ float gred[4];
    __shared__ float gored[4][HD];
    int blk = blockIdx.x;
    if (blk < 1024) {               // hist: xcd-pinned bh
        int xcd = blk & 7, i = blk >> 3;
        int bh = xcd + 8 * (i & 1);
        int rem = i >> 1;
        int y = rem & 15, ks = rem >> 4;
        attn_self_body(smem, qkv, vth, opart_h, lpart_h, NH, 0, bh, y, ks);
    } else if (blk < 1280) {        // path
        blk -= 1024;
        int xcd = blk & 7, i = blk >> 3;
        int bh = xcd + 8 * (i & 1);
        int rem = i >> 1;
        int y = rem & 3, ks = rem >> 2;
        attn_self_body(smem, qkv, vtp, opart_p, lpart_p, NP, M_HIST, bh, y, ks);
    } else {                        // global
        blk -= 1280;
        int bh = blk & 15, chunk = blk >> 4;
        attn_global_body(gqs, gps, gred, gored, qkv, gm, gl, go, bh, chunk);
    }
}

// ---------------- merged epilogue: global reduce (first) | hist combine | path combine ----------------
__global__ __launch_bounds__(256)
void epilogue2(const u16* __restrict__ opart_h, const float* __restrict__ lpart_h,
               const u16* __restrict__ opart_p, const float* __restrict__ lpart_p,
               const float* __restrict__ gm, const float* __restrict__ gl,
               const float* __restrict__ go, u16* __restrict__ xattn)
{
    const int blk = blockIdx.x;
    const int t = threadIdx.x;
    if (blk < 4) {
        int gid = blk * 256 + t;
        int bh = gid >> 6, d = gid & 63;
        int b = bh >> 3, h = bh & 7;
        float m = -INFINITY;
#pragma unroll
        for (int c = 0; c < NCHUNK; c++) m = fmaxf(m, gm[bh * NCHUNK + c]);
        float den = 0.f, acc = 0.f;
#pragma unroll
        for (int c = 0; c < NCHUNK; c++) {
            float w = __expf(gm[bh * NCHUNK + c] - m);
            den += w * gl[bh * NCHUNK + c];
            acc += w * go[((size_t)bh * NCHUNK + c) * HD + d];
        }
        xattn[(size_t)(M_HIST + M_PATH + b) * CDIM + h * HD + d] = f2bf(acc / den);
    } else {
        const u16* opart; const float* lpart; int row_base, idx;
        if (blk < 4 + 8192) { opart = opart_h; lpart = lpart_h; row_base = 0;      idx = (blk - 4) * 256 + t; }
        else                { opart = opart_p; lpart = lpart_p; row_base = M_HIST; idx = (blk - 4 - 8192) * 256 + t; }
        int grow = idx >> 9;
        int c = idx & 511;
        int h = c >> 6, d = c & 63;
        size_t pb = ((size_t)grow * HEADS + h) * KS;
        float O = 0.f, L = 0.f;
#pragma unroll
        for (int s = 0; s < KS; s++) {
            O += bf2f(opart[(pb + s) * HD + d]);
            L += lpart[pb + s];
        }
        xattn[(size_t)(row_base + grow) * CDIM + c] = f2bf(O / L);
    }
}

// ---------------- launch ----------------
extern "C" void kernel_launch(void* const* d_in, const int* in_sizes, int n_in,
                              void* d_out, int out_size, void* d_ws, size_t ws_size,
                              hipStream_t stream)
{
    const float* hist  = (const float*)d_in[0];
    const float* path  = (const float*)d_in[1];
    const float* glob  = (const float*)d_in[2];
    const float* wqkv  = (const float*)d_in[3];
    const float* wproj = (const float*)d_in[4];
    const float* bias  = (const float*)d_in[5];
    float* out = (float*)d_out;

    u16* xcat = (u16*)d_ws;
    u16* wq   = xcat + (size_t)M_PAD * CDIM;
    u16* wp   = wq   + (size_t)K3 * CDIM;
    u16* qkvb = wp   + (size_t)CDIM * CDIM;
    u16* vth  = qkvb + (size_t)M_PAD * K3;
    u16* vtp  = vth  + (size_t)NB * HEADS * HD * NH;
    u16* xatt = vtp  + (size_t)NB * HEADS * HD * NP;
    float* gm = (float*)(xatt + (size_t)M_PAD * CDIM);
    float* gl = gm + NB * HEADS * NCHUNK;
    float* go = gl + NB * HEADS * NCHUNK;
    float* lpart_h = go + (size_t)NB * HEADS * NCHUNK * HD;
    float* lpart_p = lpart_h + (size_t)M_HIST * HEADS * KS;
    u16* opart_h = (u16*)(lpart_p + (size_t)M_PATH * HEADS * KS);
    u16* opart_p = opart_h + (size_t)M_HIST * HEADS * KS * HD;

    {
        int quads = (M_PAD * CDIM + K3 * CDIM + CDIM * CDIM) / 4;
        convert_kernel<<<(quads + 255) / 256, 256, 0, stream>>>(hist, path, glob, wqkv, wproj,
                                                                xcat, wq, wp);
    }
    gemm128<0><<<dim3(K3 / 128, M_PAD / 128), 256, 0, stream>>>(xcat, wq, qkvb, nullptr, nullptr, K3,
                                                                vth, vtp);
    attn_mega<<<1456, 256, 0, stream>>>(qkvb, vth, vtp, opart_h, lpart_h, opart_p, lpart_p,
                                        gm, gl, go);
    epilogue2<<<4 + 8192 + 2048, 256, 0, stream>>>(opart_h, lpart_h, opart_p, lpart_p,
                                                   gm, gl, go, xatt);
    gemm128<1><<<dim3(CDIM / 128, M_PAD / 128), 256, 0, stream>>>(xatt, wp, nullptr, out, bias, CDIM,
                                                                  nullptr, nullptr);
}